// Round 13
// baseline (46.270 us; speedup 1.0000x reference)
//
#include <hip/hip_runtime.h>
#include <hip/hip_fp16.h>

// 21-qubit QNN, 3 layers, 2 sweeps (light-cone fusion).
// Sweep A (NEW): 13-bit window y[0:12], 256 blocks x 1024 threads, 8 amps/thread
// (3 reg bits) -> 16 waves/CU (4/SIMD, 2x the old occupancy). 35 Rots in 12
// groups of <=3, CNOT folds attached to the 11 LDS exchanges (re-derived,
// dependency-checked). Same global gate order as the verified 4-bit schedule.
// Sweep B: unchanged from R12 (verified). z layout unchanged:
// z[0:4]=y[8:12] (asc), z[5:12]=y[13:20], z[13:20]=y[0:7]

typedef __attribute__((ext_vector_type(2))) float f2;

union H4 { int4 i4; __half2 h[4]; };
union H2 { int2 i2; __half2 h[2]; };

__device__ __forceinline__ f2 mkf2(float a, float b) { f2 r; r.x = a; r.y = b; return r; }

__device__ __forceinline__ unsigned SWZ(unsigned i) {
    return i ^ ((i >> 4) & 0xFu) ^ ((i >> 8) & 0xFu);   // bank spread, bijective
}
__device__ __forceinline__ unsigned f1(unsigned x, unsigned m) {
    return x ^ ((x >> 1) & m);
}
// mA = LATER-in-time CNOT group (applied first in the gather), mB = earlier.
__device__ __forceinline__ unsigned f2fold(unsigned x, unsigned mA, unsigned mB) {
    unsigned t = x ^ ((x >> 1) & mA);
    return t ^ ((t >> 1) & mB);
}

__device__ __forceinline__ void crot(const f2 u00, const f2 u01,
                                     const f2 u10, const f2 u11,
                                     f2& a, f2& b) {
    const f2 sa = mkf2(-a.y, a.x);
    const f2 sb = mkf2(-b.y, b.x);
    f2 na = u00.x * a;
    na += u00.y * sa;
    na += u01.x * b;
    na += u01.y * sb;
    f2 nb = u10.x * a;
    nb += u10.y * sa;
    nb += u11.x * b;
    nb += u11.y * sb;
    a = na; b = nb;
}

// 8-amp register block: up to 3 Rots; id k acts on reg-bit k.
__device__ __forceinline__ void apply3(f2 v[8], const f2* gU,
                                       int id0, int id1, int id2) {
    const int ids[3] = {id0, id1, id2};
#pragma unroll
    for (int kk = 0; kk < 3; ++kk) {
        const int id = ids[kk];
        if (id < 0) continue;
        const f2 u00 = gU[4*id+0], u01 = gU[4*id+1];
        const f2 u10 = gU[4*id+2], u11 = gU[4*id+3];
#pragma unroll
        for (int x = 0; x < 8; ++x)
            if (!(x & (1 << kk)))
                crot(u00, u01, u10, u11, v[x], v[x | (1 << kk)]);
    }
}

// 16-amp block for sweepB (unchanged)
__device__ __forceinline__ void apply4(f2 v[16], const f2* gU,
                                       int id0, int id1, int id2, int id3) {
    const int ids[4] = {id0, id1, id2, id3};
#pragma unroll
    for (int kk = 0; kk < 4; ++kk) {
        const int id = ids[kk];
        if (id < 0) continue;
        const f2 u00 = gU[4*id+0], u01 = gU[4*id+1];
        const f2 u10 = gU[4*id+2], u11 = gU[4*id+3];
#pragma unroll
        for (int x = 0; x < 16; ++x)
            if (!(x & (1 << kk)))
                crot(u00, u01, u10, u11, v[x], v[x | (1 << kk)]);
    }
}

__device__ __forceinline__ void prep_gates_lds(const float* __restrict__ param,
                                               f2* gU, unsigned tid) {
    if (tid < 63) {
        float phi = param[3*tid+0], th = param[3*tid+1], om = param[3*tid+2];
        float s, c;   __sincosf(0.5f*th, &s, &c);
        float sp, cp; __sincosf(-0.5f*(phi+om), &sp, &cp);
        float sm, cm; __sincosf( 0.5f*(phi-om), &sm, &cm);
        gU[4*tid+0] = mkf2( cp*c,  sp*c);
        gU[4*tid+1] = mkf2(-cm*s, -sm*s);
        gU[4*tid+2] = mkf2( cm*s, -sm*s);
        gU[4*tid+3] = mkf2( cp*c, -sp*c);
    }
}

// ---- sweepA mappings: (t 10b, r 3b) -> 13-bit e.  regs listed ascending ----
__device__ __forceinline__ unsigned M1 (unsigned t, unsigned r){ return (t<<3)|r; }                                    // e{0,1,2}
__device__ __forceinline__ unsigned M2 (unsigned t, unsigned r){ return (t&7u) | (r<<3) | ((t>>3)<<6); }               // e{3,4,5}
__device__ __forceinline__ unsigned M3 (unsigned t, unsigned r){ return (t&63u) | (r<<6) | ((t>>6)<<9); }              // e{6,7,8}
__device__ __forceinline__ unsigned M4 (unsigned t, unsigned r){ return (t&511u) | (r<<9) | ((t>>9)<<12); }            // e{9,10,11}
__device__ __forceinline__ unsigned M5 (unsigned t, unsigned r){ return (t&127u) | (r<<7) | ((t>>7)<<10); }            // e{7,8,9}
__device__ __forceinline__ unsigned M6 (unsigned t, unsigned r){                                                       // e{5,6,12}
    return (t&31u) | ((r&1u)<<5) | (((r>>1)&1u)<<6) | (((t>>5)&31u)<<7) | (((r>>2)&1u)<<12);
}
__device__ __forceinline__ unsigned M7 (unsigned t, unsigned r){                                                       // e{4,10,11}
    return (t&15u) | ((r&1u)<<4) | (((t>>4)&31u)<<5) | (((r>>1)&1u)<<10) | (((r>>2)&1u)<<11) | ((t>>9)<<12);
}
__device__ __forceinline__ unsigned M8 (unsigned t, unsigned r){ return (t&1u) | (r<<1) | ((t>>1)<<4); }               // e{1,2,3}
__device__ __forceinline__ unsigned M9 (unsigned t, unsigned r){                                                       // e{0,7,8}
    return (r&1u) | ((t&63u)<<1) | (((r>>1)&1u)<<7) | (((r>>2)&1u)<<8) | ((t>>6)<<9);
}
__device__ __forceinline__ unsigned M10(unsigned t, unsigned r){                                                       // e{5,6,9}
    return (t&31u) | ((r&1u)<<5) | (((r>>1)&1u)<<6) | (((t>>5)&3u)<<7) | (((r>>2)&1u)<<9) | ((t>>7)<<10);
}
__device__ __forceinline__ unsigned M11(unsigned t, unsigned r){ return (t&3u) | (r<<2) | ((t>>2)<<5); }               // e{2,3,4}
__device__ __forceinline__ unsigned M12(unsigned t, unsigned r){                                                       // e{0,1,8}
    return (r&1u) | (((r>>1)&1u)<<1) | (((t>>4)&63u)<<2) | (((r>>2)&1u)<<8) | ((t&15u)<<9);
}
// ---- sweepB mappings (11-bit, unchanged from R12) ----
__device__ __forceinline__ unsigned E1Bn(unsigned t, unsigned r){ return (t&127u) | (r<<7); }
__device__ __forceinline__ unsigned E2Bn(unsigned t, unsigned r){ return (t&7u) | (r<<3) | ((t>>3)<<7); }
__device__ __forceinline__ unsigned E5Bn(unsigned t, unsigned r){
    return (t&3u) | ((r&1u)<<2) | (((t>>2)&31u)<<3) | (((r>>1)&1u)<<8) | (((r>>2)&1u)<<9) | (((r>>3)&1u)<<10);
}
__device__ __forceinline__ unsigned E6Bn(unsigned t, unsigned r){ return (t&15u) | (r<<4) | ((t>>4)<<8); }
__device__ __forceinline__ unsigned E7Bn(unsigned t, unsigned r){ return (r&15u) | (t<<4); }

// write current mapping, barrier, read next mapping. Next phase uses OTHER buf.
#define PHASE8(BUF, EW, ER) do { \
    _Pragma("unroll") for (int r = 0; r < 8; ++r) { unsigned e_ = (EW); BUF[SWZ(e_)] = v[r]; } \
    __syncthreads(); \
    _Pragma("unroll") for (int r = 0; r < 8; ++r) { unsigned e_ = (ER); v[r] = BUF[SWZ(e_)]; } \
    } while (0)
#define PHASE16(BUF, EW, ER) do { \
    _Pragma("unroll") for (int r = 0; r < 16; ++r) { unsigned e_ = (EW); BUF[SWZ(e_)] = v[r]; } \
    __syncthreads(); \
    _Pragma("unroll") for (int r = 0; r < 16; ++r) { unsigned e_ = (ER); v[r] = BUF[SWZ(e_)]; } \
    } while (0)

__global__ __launch_bounds__(1024) void sweepA(const float* __restrict__ feat,
                                               const float* __restrict__ param,
                                               __half2* __restrict__ zbuf,
                                               float* __restrict__ out) {
    __shared__ f2 sh0[8192];
    __shared__ f2 sh1[8192];
    __shared__ f2 gU[252];
    const unsigned tid = threadIdx.x;              // 10 bits
    const unsigned F = blockIdx.x;                 // y bits 13..20
    if (F == 0 && tid == 0) out[0] = 0.0f;

    // feat load first (M1 layout: 8 consecutive floats); sincos overlaps latency
    float4 f0, fA;
    {
        const float4* fp = (const float4*)(feat + (((size_t)F) << 13) + (tid << 3));
        f0 = fp[0]; fA = fp[1];
    }
    prep_gates_lds(param, gU, tid);

    f2 v[8];
    v[0] = mkf2(f0.x, 0.f); v[1] = mkf2(f0.y, 0.f);
    v[2] = mkf2(f0.z, 0.f); v[3] = mkf2(f0.w, 0.f);
    v[4] = mkf2(fA.x, 0.f); v[5] = mkf2(fA.y, 0.f);
    v[6] = mkf2(fA.z, 0.f); v[7] = mkf2(fA.w, 0.f);
    __syncthreads();                               // gU ready

    apply3(v, gU, 20, 19, 18);                     // g1: R0 q20,q19,q18 on e0,e1,e2
    PHASE8(sh0, M1(tid,r), M2(tid,r));
    apply3(v, gU, 17, 16, 15);                     // g2: R0 q17,q16,q15
    PHASE8(sh1, M2(tid,r), M3(tid,r));
    apply3(v, gU, 14, 13, 12);                     // g3: R0 q14,q13,q12
    PHASE8(sh0, M3(tid,r), M4(tid,r));
    apply3(v, gU, 11, 10, 9);                      // g4: R0 q11,q10,q9
    // F1: O0{(11,12)..(19,20)} later (0x155), E0{(10,11)..(18,19)} earlier (0x2AA)
    PHASE8(sh1, M4(tid,r), f2fold(M5(tid,r), 0x155u, 0x2AAu));
    apply3(v, gU, 34, 33, 32);                     // g5: R1 q13,q12,q11 on e7,e8,e9
    PHASE8(sh0, M5(tid,r), M6(tid,r));             // no fold
    apply3(v, gU, 36, 35, 8);                      // g6: R1 q15(e5), R1 q14(e6), R0 q8(e12)
    // F2: O0(9,10) later (0x400), E0(8,9) earlier (0x800)
    PHASE8(sh1, M6(tid,r), f2fold(M7(tid,r), 0x400u, 0x800u));
    apply3(v, gU, 37, 31, 30);                     // g7: R1 q16(e4), q10(e10), q9(e11)
    // F3: O1{(11,12),(13,14)} later (0x140), E1{(10,11),(12,13),(14,15)} earlier (0x2A0)
    PHASE8(sh0, M7(tid,r), f2fold(M8(tid,r), 0x140u, 0x2A0u));
    apply3(v, gU, 40, 39, 38);                     // g8: R1 q19(e1), q18(e2), q17(e3)
    // F4: O1{(15,16),(17,18)} later (0x014), E1{(16,17),(18,19)} earlier (0x00A)
    PHASE8(sh1, M8(tid,r), f2fold(M9(tid,r), 0x014u, 0x00Au));
    apply3(v, gU, 41, 55, 54);                     // g9: R1 q20(e0), R2 q13(e7), R2 q12(e8)
    // F5: O1(19,20) tgt e0 + E2(12,13) tgt e7 (disjoint)
    PHASE8(sh0, M9(tid,r), f1(M10(tid,r), 0x081u));
    apply3(v, gU, 57, 56, 53);                     // g10: R2 q15(e5), q14(e6), q11(e9)
    // F6: O2(13,14) later (0x040), E2(14,15) earlier (0x020)
    PHASE8(sh1, M10(tid,r), f2fold(M11(tid,r), 0x040u, 0x020u));
    apply3(v, gU, 60, 59, 58);                     // g11: R2 q18(e2), q17(e3), q16(e4)
    // F7: O2(15,16) later (0x010), E2(16,17) earlier (0x008)
    PHASE8(sh0, M11(tid,r), f2fold(M12(tid,r), 0x010u, 0x008u));
    apply3(v, gU, 62, 61, -1);                     // g12: R2 q20(e0), q19(e1); e8 spectator
    // leftover E2(18,19), O2(17,18),(19,20) -> sweepB block perm (unchanged)

    {   // store: z0=e8(r2), z[1:4]=e[9:12]=t[0:3], z[5:12]=F, z13=e0(r0),
        // z14=e1(r1), z[15:20]=e[2:7]=t[4:9].  int2 = pair along z0.
        int2* zb2 = (int2*)zbuf;
        const unsigned sbase = (tid & 15u) | (F << 4) | (((tid >> 4) & 63u) << 14);
#pragma unroll
        for (unsigned p = 0; p < 4; ++p) {         // p = (r1<<1)|r0
            H2 y;
            y.h[0] = __float22half2_rn(make_float2(v[p].x,      v[p].y));       // r2=0
            y.h[1] = __float22half2_rn(make_float2(v[p | 4u].x, v[p | 4u].y));  // r2=1
            zb2[sbase | ((p & 1u) << 12) | (((p >> 1) & 1u) << 13)] = y.i2;
        }
    }
}

__global__ __launch_bounds__(128, 2) void sweepB(const __half2* __restrict__ zbuf,
                                                 const float* __restrict__ param,
                                                 float* __restrict__ out) {
    __shared__ f2 sh0[2048];
    __shared__ f2 sh1[2048];
    __shared__ f2 gU[252];
    __shared__ float wsum[2];
    const unsigned tid = threadIdx.x;              // 7 bits
    const unsigned b = ((blockIdx.x & 7u) << 6) | (blockIdx.x >> 3);  // XCD swizzle
    const unsigned B8 = (b >> 2) << 1;             // y[0:7] with y0=0
    const unsigned t0 = B8 ^ ((B8 >> 1) & 5u);
    const unsigned Bp8 = t0 ^ ((t0 >> 1) & 2u);
    const unsigned zbase = (b & 1u) | (((b >> 1) & 1u) << 1) | (Bp8 << 13);

    __half2 raw[16];
    {
        const __half2* zp = zbuf + zbase;
#pragma unroll
        for (int r = 0; r < 16; ++r) {
            unsigned ee = tid | ((unsigned)r << 7);
            raw[r] = zp[(size_t)ee << 2];
        }
    }
    prep_gates_lds(param, gU, tid);

    f2 v[16];
#pragma unroll
    for (int r = 0; r < 16; ++r) {
        float2 t2 = __half22float2(raw[r]);
        v[r] = mkf2(t2.x, t2.y);
    }
    __syncthreads();                                // gU ready
    apply4(v, gU, 3, 2, 1, 0);                      // R0 q3,q2,q1,q0
    PHASE16(sh1, E1Bn(tid,r), f1(E2Bn(tid,r), 0x280u));
    apply4(v, gU, 7, 6, 5, 4);                      // R0 q7..q4
    PHASE16(sh0, E2Bn(tid,r), f2fold(E1Bn(tid,r), 0x154u, 0x028u));
    apply4(v, gU, 24, 23, 22, 21);                  // R1 q3..q0
    PHASE16(sh1, E1Bn(tid,r), f1(E2Bn(tid,r), 0x280u));
    apply4(v, gU, 28, 27, 26, 25);                  // R1 q7..q4
    PHASE16(sh0, E2Bn(tid,r), f2fold(E5Bn(tid,r), 0x150u, 0x028u));
    apply4(v, gU, 29, 44, 43, 42);                  // R1 q8 ; R2 q2,q1,q0
    PHASE16(sh1, E5Bn(tid,r), f2fold(E6Bn(tid,r), 0x005u, 0x002u));
    apply4(v, gU, 48, 47, 46, 45);                  // R2 q6,q5,q4,q3
    PHASE16(sh0, E6Bn(tid,r), E7Bn(tid,r));         // no fold
    apply4(v, gU, 52, 51, 50, 49);                  // R2 q10,q9,q8,q7
    float acc = 0.f;
#pragma unroll
    for (int r = 0; r < 16; ++r) acc += v[r].x*v[r].x + v[r].y*v[r].y;
    for (int off = 32; off; off >>= 1) acc += __shfl_down(acc, off);
    if ((tid & 63u) == 0) wsum[tid >> 6] = acc;
    __syncthreads();
    if (tid == 0) atomicAdd(out, wsum[0] + wsum[1]);
}

extern "C" void kernel_launch(void* const* d_in, const int* in_sizes, int n_in,
                              void* d_out, int out_size, void* d_ws, size_t ws_size,
                              hipStream_t stream) {
    const float* feat  = (const float*)d_in[0];
    const float* param = (const float*)d_in[1];
    float* out = (float*)d_out;
    __half2* zbuf = (__half2*)d_ws;                // 2^21 * 4B = 8 MB

    sweepA<<<256, 1024, 0, stream>>>(feat, param, zbuf, out);
    sweepB<<<512, 128, 0, stream>>>(zbuf, param, out);
}

// Round 14
// 43.047 us; speedup vs baseline: 1.0749x; 1.0749x over previous
//
#include <hip/hip_runtime.h>
#include <hip/hip_fp16.h>

// 21-qubit QNN, 3 layers, 2 sweeps (light-cone fusion). Verified R11/R12
// structure; THIS ROUND: all LDS exchange addresses hoisted via GF(2)
// linearity:  addr(tid,r) = G(tid) ^ G_r,  G_r compile-time.
// (All index maps are XOR-linear: disjoint-field bit splices, XOR folds,
// XOR swizzle; E(0,0)=0.)
// z layout: z[0:4]=y[8:12] (asc), z[5:12]=y[13:20], z[13:20]=y[0:7]

typedef __attribute__((ext_vector_type(2))) float f2;

union H4 { int4 i4; __half2 h[4]; };
union H2 { int2 i2; __half2 h[2]; };

__device__ __forceinline__ f2 mkf2(float a, float b) { f2 r; r.x = a; r.y = b; return r; }

__device__ __forceinline__ unsigned SWZ(unsigned i) {
    return i ^ ((i >> 4) & 0xFu) ^ ((i >> 8) & 0xFu);   // bank spread, XOR-linear
}
__device__ __forceinline__ unsigned f1(unsigned x, unsigned m) {
    return x ^ ((x >> 1) & m);
}
// mA = LATER-in-time CNOT group (applied first in the gather), mB = earlier.
__device__ __forceinline__ unsigned f2fold(unsigned x, unsigned mA, unsigned mB) {
    unsigned t = x ^ ((x >> 1) & mA);
    return t ^ ((t >> 1) & mB);
}

__device__ __forceinline__ void crot(const f2 u00, const f2 u01,
                                     const f2 u10, const f2 u11,
                                     f2& a, f2& b) {
    const f2 sa = mkf2(-a.y, a.x);
    const f2 sb = mkf2(-b.y, b.x);
    f2 na = u00.x * a;
    na += u00.y * sa;
    na += u01.x * b;
    na += u01.y * sb;
    f2 nb = u10.x * a;
    nb += u10.y * sa;
    nb += u11.x * b;
    nb += u11.y * sb;
    a = na; b = nb;
}

__device__ __forceinline__ void apply4(f2 v[16], const f2* gU,
                                       int id0, int id1, int id2, int id3) {
    const int ids[4] = {id0, id1, id2, id3};
#pragma unroll
    for (int kk = 0; kk < 4; ++kk) {
        const int id = ids[kk];
        if (id < 0) continue;
        const f2 u00 = gU[4*id+0], u01 = gU[4*id+1];
        const f2 u10 = gU[4*id+2], u11 = gU[4*id+3];
#pragma unroll
        for (int x = 0; x < 16; ++x)
            if (!(x & (1 << kk)))
                crot(u00, u01, u10, u11, v[x], v[x | (1 << kk)]);
    }
}

__device__ __forceinline__ void prep_gates_lds(const float* __restrict__ param,
                                               f2* gU, unsigned tid) {
    if (tid < 63) {
        float phi = param[3*tid+0], th = param[3*tid+1], om = param[3*tid+2];
        float s, c;   __sincosf(0.5f*th, &s, &c);
        float sp, cp; __sincosf(-0.5f*(phi+om), &sp, &cp);
        float sm, cm; __sincosf( 0.5f*(phi-om), &sm, &cm);
        gU[4*tid+0] = mkf2( cp*c,  sp*c);
        gU[4*tid+1] = mkf2(-cm*s, -sm*s);
        gU[4*tid+2] = mkf2( cm*s, -sm*s);
        gU[4*tid+3] = mkf2( cp*c, -sp*c);
    }
}

// ---- sweep A mappings: (t 9b, r 4b) -> 13-bit e (disjoint fields, E(0,0)=0) ----
__device__ __forceinline__ unsigned E1A (unsigned t, unsigned r){ return (t<<4)|r; }
__device__ __forceinline__ unsigned E2A (unsigned t, unsigned r){ return ((t>>4)<<8)|(r<<4)|(t&15u); }
__device__ __forceinline__ unsigned E3A (unsigned t, unsigned r){ return ((t>>8)<<12)|(r<<8)|(t&255u); }
__device__ __forceinline__ unsigned E4A (unsigned t, unsigned r){
    return (t&127u) | (((t>>7)&3u)<<10) | ((r&1u)<<7) | (((r>>1)&1u)<<8) | (((r>>2)&1u)<<9) | (((r>>3)&1u)<<12);
}
__device__ __forceinline__ unsigned E5A (unsigned t, unsigned r){
    return (t&31u) | (((t>>5)&7u)<<7) | (((t>>8)&1u)<<12) | ((r&1u)<<5) | (((r>>1)&1u)<<6) | (((r>>2)&1u)<<10) | (((r>>3)&1u)<<11);
}
__device__ __forceinline__ unsigned E6A (unsigned t, unsigned r){ return (t&1u) | (((t>>1)&255u)<<5) | (r<<1); }
__device__ __forceinline__ unsigned E7A (unsigned t, unsigned r){
    return ((t&63u)<<1) | (((t>>6)&7u)<<10) | (r&1u) | (((r>>1)&1u)<<7) | (((r>>2)&1u)<<8) | (((r>>3)&1u)<<9);
}
__device__ __forceinline__ unsigned E8A (unsigned t, unsigned r){ return (t&7u) | (((t>>3)&63u)<<7) | ((r&15u)<<3); }
__device__ __forceinline__ unsigned E11A(unsigned t, unsigned r){
    return (r&7u) | (((r>>3)&1u)<<8) | ((t&15u)<<9) | ((t>>4)<<3);
}
// ---- sweep B mappings (11-bit) ----
__device__ __forceinline__ unsigned E1Bn(unsigned t, unsigned r){ return (t&127u) | (r<<7); }
__device__ __forceinline__ unsigned E2Bn(unsigned t, unsigned r){ return (t&7u) | (r<<3) | ((t>>3)<<7); }
__device__ __forceinline__ unsigned E5Bn(unsigned t, unsigned r){
    return (t&3u) | ((r&1u)<<2) | (((t>>2)&31u)<<3) | (((r>>1)&1u)<<8) | (((r>>2)&1u)<<9) | (((r>>3)&1u)<<10);
}
__device__ __forceinline__ unsigned E6Bn(unsigned t, unsigned r){ return (t&15u) | (r<<4) | ((t>>4)<<8); }
__device__ __forceinline__ unsigned E7Bn(unsigned t, unsigned r){ return (r&15u) | (t<<4); }

// one exchange phase with hoisted linear addressing:
// addr = FW(tid,0) ^ FW(0,r)  (the latter constant-folds per unrolled r)
template<class FW, class FR>
__device__ __forceinline__ void phase16(f2* buf, f2 v[16], unsigned tid, FW fw, FR fr) {
    const unsigned wb = fw(tid, 0u);
#pragma unroll
    for (unsigned r = 0; r < 16; ++r) buf[wb ^ fw(0u, r)] = v[r];
    __syncthreads();
    const unsigned rb = fr(tid, 0u);
#pragma unroll
    for (unsigned r = 0; r < 16; ++r) v[r] = buf[rb ^ fr(0u, r)];
}

__global__ __launch_bounds__(512, 2) void sweepA(const float* __restrict__ feat,
                                                 const float* __restrict__ param,
                                                 __half2* __restrict__ zbuf,
                                                 float* __restrict__ out) {
    __shared__ f2 sh0[8192];
    __shared__ f2 sh1[8192];
    __shared__ f2 gU[252];
    const unsigned tid = threadIdx.x;
    const unsigned F = blockIdx.x;                 // y bits 13..20
    if (F == 0 && tid == 0) out[0] = 0.0f;

    float4 fraw[4];
    {
        const float4* fp = (const float4*)(feat + (((size_t)F) << 13) + (tid << 4));
#pragma unroll
        for (int c = 0; c < 4; ++c) fraw[c] = fp[c];
    }
    prep_gates_lds(param, gU, tid);

    f2 v[16];
#pragma unroll
    for (int c = 0; c < 4; ++c) {                  // regs = y{0..3}
        v[4*c+0] = mkf2(fraw[c].x, 0.f); v[4*c+1] = mkf2(fraw[c].y, 0.f);
        v[4*c+2] = mkf2(fraw[c].z, 0.f); v[4*c+3] = mkf2(fraw[c].w, 0.f);
    }
    __syncthreads();                                // gU ready

    apply4(v, gU, 20, 19, 18, 17);                  // R0 q20,q19,q18,q17
    phase16(sh0, v, tid,
        [](unsigned t, unsigned r){ return SWZ(E1A(t,r)); },
        [](unsigned t, unsigned r){ return SWZ(E2A(t,r)); });
    apply4(v, gU, 16, 15, 14, 13);                  // R0 q16..q13
    phase16(sh1, v, tid,
        [](unsigned t, unsigned r){ return SWZ(E2A(t,r)); },
        [](unsigned t, unsigned r){ return SWZ(E3A(t,r)); });
    apply4(v, gU, 12, 11, 10, 9);                   // R0 q12..q9
    phase16(sh0, v, tid,                            // F1: O0 0x155 later, E0 0x2AA earlier
        [](unsigned t, unsigned r){ return SWZ(E3A(t,r)); },
        [](unsigned t, unsigned r){ return SWZ(f2fold(E4A(t,r), 0x155u, 0x2AAu)); });
    apply4(v, gU, 34, 33, 32, 8);                   // R1 q13,q12,q11 ; R0 q8
    phase16(sh1, v, tid,                            // F2: O0(9,10) 0x400, E0(8,9) 0x800
        [](unsigned t, unsigned r){ return SWZ(E4A(t,r)); },
        [](unsigned t, unsigned r){ return SWZ(f2fold(E5A(t,r), 0x400u, 0x800u)); });
    apply4(v, gU, 36, 35, 31, 30);                  // R1 q15,q14,q10,q9
    phase16(sh0, v, tid,                            // F3: O1 0x140, E1 0x2A0
        [](unsigned t, unsigned r){ return SWZ(E5A(t,r)); },
        [](unsigned t, unsigned r){ return SWZ(f2fold(E6A(t,r), 0x140u, 0x2A0u)); });
    apply4(v, gU, 40, 39, 38, 37);                  // R1 q19,q18,q17,q16
    phase16(sh1, v, tid,                            // F4: O1 0x014, E1 0x00A
        [](unsigned t, unsigned r){ return SWZ(E6A(t,r)); },
        [](unsigned t, unsigned r){ return SWZ(f2fold(E7A(t,r), 0x014u, 0x00Au)); });
    apply4(v, gU, 41, 55, 54, 53);                  // R1 q20 ; R2 q13,q12,q11
    phase16(sh0, v, tid,                            // F5: O1(19,20)+E2(12,13) 0x081
        [](unsigned t, unsigned r){ return SWZ(E7A(t,r)); },
        [](unsigned t, unsigned r){ return SWZ(f1(E8A(t,r), 0x081u)); });
    apply4(v, gU, 59, 58, 57, 56);                  // R2 q17,q16,q15,q14
    phase16(sh1, v, tid,                            // F6: O2 0x050, E2 0x028; store-ready layout
        [](unsigned t, unsigned r){ return SWZ(E8A(t,r)); },
        [](unsigned t, unsigned r){ return SWZ(f2fold(E11A(t,r), 0x050u, 0x028u)); });
    apply4(v, gU, 62, 61, 60, -1);                  // R2 q20,q19,q18 on e0,e1,e2; e8 spectator
    // leftover E2(18,19), O2(17,18),(19,20) -> sweepB block perm

    {   // direct int2 store; z layout:
        // z0=e8 (in-reg), z[1:4]=e[9:12]=tid&15, z[5:12]=F, z[13:15]=e[0:2]=g, z[16:20]=e[3:7]=tid>>4
        int2* zb2 = (int2*)zbuf;
        const unsigned sbase = (tid & 15u) | (F << 4) | ((tid >> 4) << 15);  // int2 units
#pragma unroll
        for (unsigned g = 0; g < 8; ++g) {
            H2 y;
            y.h[0] = __float22half2_rn(make_float2(v[g].x,      v[g].y));        // e8 = 0
            y.h[1] = __float22half2_rn(make_float2(v[g | 8u].x, v[g | 8u].y));   // e8 = 1
            zb2[sbase | (g << 12)] = y.i2;
        }
    }
}

__global__ __launch_bounds__(128, 2) void sweepB(const __half2* __restrict__ zbuf,
                                                 const float* __restrict__ param,
                                                 float* __restrict__ out) {
    __shared__ f2 sh0[2048];
    __shared__ f2 sh1[2048];
    __shared__ f2 gU[252];
    __shared__ float wsum[2];
    const unsigned tid = threadIdx.x;              // 7 bits
    const unsigned b = ((blockIdx.x & 7u) << 6) | (blockIdx.x >> 3);  // XCD swizzle
    const unsigned B8 = (b >> 2) << 1;             // y[0:7] with y0=0
    const unsigned t0 = B8 ^ ((B8 >> 1) & 5u);
    const unsigned Bp8 = t0 ^ ((t0 >> 1) & 2u);
    const unsigned zbase = (b & 1u) | (((b >> 1) & 1u) << 1) | (Bp8 << 13);

    __half2 raw[16];
    {
        const __half2* zp = zbuf + zbase + (tid << 2);
#pragma unroll
        for (int r = 0; r < 16; ++r) raw[r] = zp[(size_t)r << 9];
    }
    prep_gates_lds(param, gU, tid);

    f2 v[16];
#pragma unroll
    for (int r = 0; r < 16; ++r) {
        float2 t2 = __half22float2(raw[r]);
        v[r] = mkf2(t2.x, t2.y);
    }
    __syncthreads();                                // gU ready
    apply4(v, gU, 3, 2, 1, 0);                      // R0 q3,q2,q1,q0
    phase16(sh1, v, tid,
        [](unsigned t, unsigned r){ return SWZ(E1Bn(t,r)); },
        [](unsigned t, unsigned r){ return SWZ(f1(E2Bn(t,r), 0x280u)); });
    apply4(v, gU, 7, 6, 5, 4);                      // R0 q7..q4
    phase16(sh0, v, tid,
        [](unsigned t, unsigned r){ return SWZ(E2Bn(t,r)); },
        [](unsigned t, unsigned r){ return SWZ(f2fold(E1Bn(t,r), 0x154u, 0x028u)); });
    apply4(v, gU, 24, 23, 22, 21);                  // R1 q3..q0
    phase16(sh1, v, tid,
        [](unsigned t, unsigned r){ return SWZ(E1Bn(t,r)); },
        [](unsigned t, unsigned r){ return SWZ(f1(E2Bn(t,r), 0x280u)); });
    apply4(v, gU, 28, 27, 26, 25);                  // R1 q7..q4
    phase16(sh0, v, tid,
        [](unsigned t, unsigned r){ return SWZ(E2Bn(t,r)); },
        [](unsigned t, unsigned r){ return SWZ(f2fold(E5Bn(t,r), 0x150u, 0x028u)); });
    apply4(v, gU, 29, 44, 43, 42);                  // R1 q8 ; R2 q2,q1,q0
    phase16(sh1, v, tid,
        [](unsigned t, unsigned r){ return SWZ(E5Bn(t,r)); },
        [](unsigned t, unsigned r){ return SWZ(f2fold(E6Bn(t,r), 0x005u, 0x002u)); });
    apply4(v, gU, 48, 47, 46, 45);                  // R2 q6,q5,q4,q3
    phase16(sh0, v, tid,
        [](unsigned t, unsigned r){ return SWZ(E6Bn(t,r)); },
        [](unsigned t, unsigned r){ return SWZ(E7Bn(t,r)); });
    apply4(v, gU, 52, 51, 50, 49);                  // R2 q10,q9,q8,q7
    // final E2/O2 inside window: perms not touching y0 -> sum-invariant, skip
    float acc = 0.f;
#pragma unroll
    for (int r = 0; r < 16; ++r) acc += v[r].x*v[r].x + v[r].y*v[r].y;
    for (int off = 32; off; off >>= 1) acc += __shfl_down(acc, off);
    if ((tid & 63u) == 0) wsum[tid >> 6] = acc;
    __syncthreads();
    if (tid == 0) atomicAdd(out, wsum[0] + wsum[1]);
}

extern "C" void kernel_launch(void* const* d_in, const int* in_sizes, int n_in,
                              void* d_out, int out_size, void* d_ws, size_t ws_size,
                              hipStream_t stream) {
    const float* feat  = (const float*)d_in[0];
    const float* param = (const float*)d_in[1];
    float* out = (float*)d_out;
    __half2* zbuf = (__half2*)d_ws;                // 2^21 * 4B = 8 MB

    sweepA<<<256, 512, 0, stream>>>(feat, param, zbuf, out);
    sweepB<<<512, 128, 0, stream>>>(zbuf, param, out);
}

// Round 15
// 43.028 us; speedup vs baseline: 1.0753x; 1.0004x over previous
//
#include <hip/hip_runtime.h>
#include <hip/hip_fp16.h>

// 21-qubit QNN, 3 layers, 2 sweeps (light-cone fusion). R14 structure
// (XOR-linear hoisted addressing) + THIS ROUND: barrier elision on the two
// provably intra-wave exchanges (sweepA P1: wave id at e[10:12] in both
// layouts; sweepB last: partner thread preserves wave bit). Per-wave DS
// ordering + compiler lgkmcnt covers the in-wave read-after-write; the next
// reuse of the buffer is fenced by the following phase's barrier.
// z layout: z[0:4]=y[8:12] (asc), z[5:12]=y[13:20], z[13:20]=y[0:7]

typedef __attribute__((ext_vector_type(2))) float f2;

union H4 { int4 i4; __half2 h[4]; };
union H2 { int2 i2; __half2 h[2]; };

__device__ __forceinline__ f2 mkf2(float a, float b) { f2 r; r.x = a; r.y = b; return r; }

__device__ __forceinline__ unsigned SWZ(unsigned i) {
    return i ^ ((i >> 4) & 0xFu) ^ ((i >> 8) & 0xFu);   // bank spread, XOR-linear (bits 0-3 only)
}
__device__ __forceinline__ unsigned f1(unsigned x, unsigned m) {
    return x ^ ((x >> 1) & m);
}
// mA = LATER-in-time CNOT group (applied first in the gather), mB = earlier.
__device__ __forceinline__ unsigned f2fold(unsigned x, unsigned mA, unsigned mB) {
    unsigned t = x ^ ((x >> 1) & mA);
    return t ^ ((t >> 1) & mB);
}

__device__ __forceinline__ void crot(const f2 u00, const f2 u01,
                                     const f2 u10, const f2 u11,
                                     f2& a, f2& b) {
    const f2 sa = mkf2(-a.y, a.x);
    const f2 sb = mkf2(-b.y, b.x);
    f2 na = u00.x * a;
    na += u00.y * sa;
    na += u01.x * b;
    na += u01.y * sb;
    f2 nb = u10.x * a;
    nb += u10.y * sa;
    nb += u11.x * b;
    nb += u11.y * sb;
    a = na; b = nb;
}

__device__ __forceinline__ void apply4(f2 v[16], const f2* gU,
                                       int id0, int id1, int id2, int id3) {
    const int ids[4] = {id0, id1, id2, id3};
#pragma unroll
    for (int kk = 0; kk < 4; ++kk) {
        const int id = ids[kk];
        if (id < 0) continue;
        const f2 u00 = gU[4*id+0], u01 = gU[4*id+1];
        const f2 u10 = gU[4*id+2], u11 = gU[4*id+3];
#pragma unroll
        for (int x = 0; x < 16; ++x)
            if (!(x & (1 << kk)))
                crot(u00, u01, u10, u11, v[x], v[x | (1 << kk)]);
    }
}

__device__ __forceinline__ void prep_gates_lds(const float* __restrict__ param,
                                               f2* gU, unsigned tid) {
    if (tid < 63) {
        float phi = param[3*tid+0], th = param[3*tid+1], om = param[3*tid+2];
        float s, c;   __sincosf(0.5f*th, &s, &c);
        float sp, cp; __sincosf(-0.5f*(phi+om), &sp, &cp);
        float sm, cm; __sincosf( 0.5f*(phi-om), &sm, &cm);
        gU[4*tid+0] = mkf2( cp*c,  sp*c);
        gU[4*tid+1] = mkf2(-cm*s, -sm*s);
        gU[4*tid+2] = mkf2( cm*s, -sm*s);
        gU[4*tid+3] = mkf2( cp*c, -sp*c);
    }
}

// ---- sweep A mappings: (t 9b, r 4b) -> 13-bit e (disjoint fields, E(0,0)=0) ----
__device__ __forceinline__ unsigned E1A (unsigned t, unsigned r){ return (t<<4)|r; }
__device__ __forceinline__ unsigned E2A (unsigned t, unsigned r){ return ((t>>4)<<8)|(r<<4)|(t&15u); }
__device__ __forceinline__ unsigned E3A (unsigned t, unsigned r){ return ((t>>8)<<12)|(r<<8)|(t&255u); }
__device__ __forceinline__ unsigned E4A (unsigned t, unsigned r){
    return (t&127u) | (((t>>7)&3u)<<10) | ((r&1u)<<7) | (((r>>1)&1u)<<8) | (((r>>2)&1u)<<9) | (((r>>3)&1u)<<12);
}
__device__ __forceinline__ unsigned E5A (unsigned t, unsigned r){
    return (t&31u) | (((t>>5)&7u)<<7) | (((t>>8)&1u)<<12) | ((r&1u)<<5) | (((r>>1)&1u)<<6) | (((r>>2)&1u)<<10) | (((r>>3)&1u)<<11);
}
__device__ __forceinline__ unsigned E6A (unsigned t, unsigned r){ return (t&1u) | (((t>>1)&255u)<<5) | (r<<1); }
__device__ __forceinline__ unsigned E7A (unsigned t, unsigned r){
    return ((t&63u)<<1) | (((t>>6)&7u)<<10) | (r&1u) | (((r>>1)&1u)<<7) | (((r>>2)&1u)<<8) | (((r>>3)&1u)<<9);
}
__device__ __forceinline__ unsigned E8A (unsigned t, unsigned r){ return (t&7u) | (((t>>3)&63u)<<7) | ((r&15u)<<3); }
__device__ __forceinline__ unsigned E11A(unsigned t, unsigned r){
    return (r&7u) | (((r>>3)&1u)<<8) | ((t&15u)<<9) | ((t>>4)<<3);
}
// ---- sweep B mappings (11-bit) ----
__device__ __forceinline__ unsigned E1Bn(unsigned t, unsigned r){ return (t&127u) | (r<<7); }
__device__ __forceinline__ unsigned E2Bn(unsigned t, unsigned r){ return (t&7u) | (r<<3) | ((t>>3)<<7); }
__device__ __forceinline__ unsigned E5Bn(unsigned t, unsigned r){
    return (t&3u) | ((r&1u)<<2) | (((t>>2)&31u)<<3) | (((r>>1)&1u)<<8) | (((r>>2)&1u)<<9) | (((r>>3)&1u)<<10);
}
__device__ __forceinline__ unsigned E6Bn(unsigned t, unsigned r){ return (t&15u) | (r<<4) | ((t>>4)<<8); }
__device__ __forceinline__ unsigned E7Bn(unsigned t, unsigned r){ return (r&15u) | (t<<4); }

// exchange with hoisted linear addressing: addr = F(tid,0) ^ F(0,r) (consts fold)
template<class FW, class FR>
__device__ __forceinline__ void phase16(f2* buf, f2 v[16], unsigned tid, FW fw, FR fr) {
    const unsigned wb = fw(tid, 0u);
#pragma unroll
    for (unsigned r = 0; r < 16; ++r) buf[wb ^ fw(0u, r)] = v[r];
    __syncthreads();
    const unsigned rb = fr(tid, 0u);
#pragma unroll
    for (unsigned r = 0; r < 16; ++r) v[r] = buf[rb ^ fr(0u, r)];
}
// intra-wave exchange: no barrier (per-wave DS ordering + lgkmcnt suffices)
template<class FW, class FR>
__device__ __forceinline__ void phase16_nb(f2* buf, f2 v[16], unsigned tid, FW fw, FR fr) {
    const unsigned wb = fw(tid, 0u);
#pragma unroll
    for (unsigned r = 0; r < 16; ++r) buf[wb ^ fw(0u, r)] = v[r];
    const unsigned rb = fr(tid, 0u);
#pragma unroll
    for (unsigned r = 0; r < 16; ++r) v[r] = buf[rb ^ fr(0u, r)];
}

__global__ __launch_bounds__(512, 2) void sweepA(const float* __restrict__ feat,
                                                 const float* __restrict__ param,
                                                 __half2* __restrict__ zbuf,
                                                 float* __restrict__ out) {
    __shared__ f2 sh0[8192];
    __shared__ f2 sh1[8192];
    __shared__ f2 gU[252];
    const unsigned tid = threadIdx.x;
    const unsigned F = blockIdx.x;                 // y bits 13..20
    if (F == 0 && tid == 0) out[0] = 0.0f;

    float4 fraw[4];
    {
        const float4* fp = (const float4*)(feat + (((size_t)F) << 13) + (tid << 4));
#pragma unroll
        for (int c = 0; c < 4; ++c) fraw[c] = fp[c];
    }
    prep_gates_lds(param, gU, tid);

    f2 v[16];
#pragma unroll
    for (int c = 0; c < 4; ++c) {                  // regs = y{0..3}
        v[4*c+0] = mkf2(fraw[c].x, 0.f); v[4*c+1] = mkf2(fraw[c].y, 0.f);
        v[4*c+2] = mkf2(fraw[c].z, 0.f); v[4*c+3] = mkf2(fraw[c].w, 0.f);
    }
    __syncthreads();                                // gU ready

    apply4(v, gU, 20, 19, 18, 17);                  // R0 q20,q19,q18,q17
    // P1 is intra-wave: wave id t[6:8] sits at e[10:12] in BOTH E1A and E2A,
    // and SWZ only perturbs bits 0-3 -> per-wave disjoint LDS slices.
    phase16_nb(sh0, v, tid,
        [](unsigned t, unsigned r){ return SWZ(E1A(t,r)); },
        [](unsigned t, unsigned r){ return SWZ(E2A(t,r)); });
    apply4(v, gU, 16, 15, 14, 13);                  // R0 q16..q13
    phase16(sh1, v, tid,                            // P2's barrier also fences sh0 reuse at P3
        [](unsigned t, unsigned r){ return SWZ(E2A(t,r)); },
        [](unsigned t, unsigned r){ return SWZ(E3A(t,r)); });
    apply4(v, gU, 12, 11, 10, 9);                   // R0 q12..q9
    phase16(sh0, v, tid,                            // F1: O0 0x155 later, E0 0x2AA earlier
        [](unsigned t, unsigned r){ return SWZ(E3A(t,r)); },
        [](unsigned t, unsigned r){ return SWZ(f2fold(E4A(t,r), 0x155u, 0x2AAu)); });
    apply4(v, gU, 34, 33, 32, 8);                   // R1 q13,q12,q11 ; R0 q8
    phase16(sh1, v, tid,                            // F2: O0(9,10) 0x400, E0(8,9) 0x800
        [](unsigned t, unsigned r){ return SWZ(E4A(t,r)); },
        [](unsigned t, unsigned r){ return SWZ(f2fold(E5A(t,r), 0x400u, 0x800u)); });
    apply4(v, gU, 36, 35, 31, 30);                  // R1 q15,q14,q10,q9
    phase16(sh0, v, tid,                            // F3: O1 0x140, E1 0x2A0
        [](unsigned t, unsigned r){ return SWZ(E5A(t,r)); },
        [](unsigned t, unsigned r){ return SWZ(f2fold(E6A(t,r), 0x140u, 0x2A0u)); });
    apply4(v, gU, 40, 39, 38, 37);                  // R1 q19,q18,q17,q16
    phase16(sh1, v, tid,                            // F4: O1 0x014, E1 0x00A
        [](unsigned t, unsigned r){ return SWZ(E6A(t,r)); },
        [](unsigned t, unsigned r){ return SWZ(f2fold(E7A(t,r), 0x014u, 0x00Au)); });
    apply4(v, gU, 41, 55, 54, 53);                  // R1 q20 ; R2 q13,q12,q11
    phase16(sh0, v, tid,                            // F5: O1(19,20)+E2(12,13) 0x081
        [](unsigned t, unsigned r){ return SWZ(E7A(t,r)); },
        [](unsigned t, unsigned r){ return SWZ(f1(E8A(t,r), 0x081u)); });
    apply4(v, gU, 59, 58, 57, 56);                  // R2 q17,q16,q15,q14
    phase16(sh1, v, tid,                            // F6: O2 0x050, E2 0x028; store-ready layout
        [](unsigned t, unsigned r){ return SWZ(E8A(t,r)); },
        [](unsigned t, unsigned r){ return SWZ(f2fold(E11A(t,r), 0x050u, 0x028u)); });
    apply4(v, gU, 62, 61, 60, -1);                  // R2 q20,q19,q18 on e0,e1,e2; e8 spectator
    // leftover E2(18,19), O2(17,18),(19,20) -> sweepB block perm

    {   // direct int2 store; z layout:
        // z0=e8 (in-reg), z[1:4]=e[9:12]=tid&15, z[5:12]=F, z[13:15]=e[0:2]=g, z[16:20]=e[3:7]=tid>>4
        int2* zb2 = (int2*)zbuf;
        const unsigned sbase = (tid & 15u) | (F << 4) | ((tid >> 4) << 15);  // int2 units
#pragma unroll
        for (unsigned g = 0; g < 8; ++g) {
            H2 y;
            y.h[0] = __float22half2_rn(make_float2(v[g].x,      v[g].y));        // e8 = 0
            y.h[1] = __float22half2_rn(make_float2(v[g | 8u].x, v[g | 8u].y));   // e8 = 1
            zb2[sbase | (g << 12)] = y.i2;
        }
    }
}

__global__ __launch_bounds__(128, 2) void sweepB(const __half2* __restrict__ zbuf,
                                                 const float* __restrict__ param,
                                                 float* __restrict__ out) {
    __shared__ f2 sh0[2048];
    __shared__ f2 sh1[2048];
    __shared__ f2 gU[252];
    __shared__ float wsum[2];
    const unsigned tid = threadIdx.x;              // 7 bits
    const unsigned b = ((blockIdx.x & 7u) << 6) | (blockIdx.x >> 3);  // XCD swizzle
    const unsigned B8 = (b >> 2) << 1;             // y[0:7] with y0=0
    const unsigned t0 = B8 ^ ((B8 >> 1) & 5u);
    const unsigned Bp8 = t0 ^ ((t0 >> 1) & 2u);
    const unsigned zbase = (b & 1u) | (((b >> 1) & 1u) << 1) | (Bp8 << 13);

    __half2 raw[16];
    {
        const __half2* zp = zbuf + zbase + (tid << 2);
#pragma unroll
        for (int r = 0; r < 16; ++r) raw[r] = zp[(size_t)r << 9];
    }
    prep_gates_lds(param, gU, tid);

    f2 v[16];
#pragma unroll
    for (int r = 0; r < 16; ++r) {
        float2 t2 = __half22float2(raw[r]);
        v[r] = mkf2(t2.x, t2.y);
    }
    __syncthreads();                                // gU ready
    apply4(v, gU, 3, 2, 1, 0);                      // R0 q3,q2,q1,q0
    phase16(sh1, v, tid,
        [](unsigned t, unsigned r){ return SWZ(E1Bn(t,r)); },
        [](unsigned t, unsigned r){ return SWZ(f1(E2Bn(t,r), 0x280u)); });
    apply4(v, gU, 7, 6, 5, 4);                      // R0 q7..q4
    phase16(sh0, v, tid,
        [](unsigned t, unsigned r){ return SWZ(E2Bn(t,r)); },
        [](unsigned t, unsigned r){ return SWZ(f2fold(E1Bn(t,r), 0x154u, 0x028u)); });
    apply4(v, gU, 24, 23, 22, 21);                  // R1 q3..q0
    phase16(sh1, v, tid,
        [](unsigned t, unsigned r){ return SWZ(E1Bn(t,r)); },
        [](unsigned t, unsigned r){ return SWZ(f1(E2Bn(t,r), 0x280u)); });
    apply4(v, gU, 28, 27, 26, 25);                  // R1 q7..q4
    phase16(sh0, v, tid,
        [](unsigned t, unsigned r){ return SWZ(E2Bn(t,r)); },
        [](unsigned t, unsigned r){ return SWZ(f2fold(E5Bn(t,r), 0x150u, 0x028u)); });
    apply4(v, gU, 29, 44, 43, 42);                  // R1 q8 ; R2 q2,q1,q0
    phase16(sh1, v, tid,
        [](unsigned t, unsigned r){ return SWZ(E5Bn(t,r)); },
        [](unsigned t, unsigned r){ return SWZ(f2fold(E6Bn(t,r), 0x005u, 0x002u)); });
    apply4(v, gU, 48, 47, 46, 45);                  // R2 q6,q5,q4,q3
    // last exchange is intra-wave: partner t' = r | t[4:6]<<4 preserves wave bit t6
    phase16_nb(sh0, v, tid,
        [](unsigned t, unsigned r){ return SWZ(E6Bn(t,r)); },
        [](unsigned t, unsigned r){ return SWZ(E7Bn(t,r)); });
    apply4(v, gU, 52, 51, 50, 49);                  // R2 q10,q9,q8,q7
    // final E2/O2 inside window: perms not touching y0 -> sum-invariant, skip
    float acc = 0.f;
#pragma unroll
    for (int r = 0; r < 16; ++r) acc += v[r].x*v[r].x + v[r].y*v[r].y;
    for (int off = 32; off; off >>= 1) acc += __shfl_down(acc, off);
    if ((tid & 63u) == 0) wsum[tid >> 6] = acc;
    __syncthreads();
    if (tid == 0) atomicAdd(out, wsum[0] + wsum[1]);
}

extern "C" void kernel_launch(void* const* d_in, const int* in_sizes, int n_in,
                              void* d_out, int out_size, void* d_ws, size_t ws_size,
                              hipStream_t stream) {
    const float* feat  = (const float*)d_in[0];
    const float* param = (const float*)d_in[1];
    float* out = (float*)d_out;
    __half2* zbuf = (__half2*)d_ws;                // 2^21 * 4B = 8 MB

    sweepA<<<256, 512, 0, stream>>>(feat, param, zbuf, out);
    sweepB<<<512, 128, 0, stream>>>(zbuf, param, out);
}

// Round 16
// 43.028 us; speedup vs baseline: 1.0753x; 1.0000x over previous
//
#include <hip/hip_runtime.h>
#include <hip/hip_fp16.h>

// 21-qubit QNN, 3 layers, 2 sweeps (light-cone fusion).
// Sweep A (NEW): gate math on MFMA. Each of the 9 verified phase-groups is a
// 16x16 complex unitary W = kron of its <=4 Rots; applied as real 32x32 bf16
// matmul ([[Wr,-Wi],[Wi,Wr]] on stacked Re/Im rows) via 2x
// mfma_f32_32x32x16_bf16 per 32-column tile. Inter-group exchange = the R15
// fold algebra inverted to scatter-on-write (XOR-linear, hoisted), LDS layout
// XOR-bank-swizzled so B-fragment ds_read_b128 is conflict-free.
// Sweep B: unchanged from R15 (verified). z layout unchanged:
// z[0:4]=y[8:12] (asc), z[5:12]=y[13:20], z[13:20]=y[0:7]

typedef __attribute__((ext_vector_type(2))) float f2;
typedef __attribute__((ext_vector_type(8))) short short8;
typedef __attribute__((ext_vector_type(16))) float f32x16;

union H2 { int2 i2; __half2 h[2]; };

__device__ __forceinline__ f2 mkf2(float a, float b) { f2 r; r.x = a; r.y = b; return r; }

// RNE f32 -> bf16 (as raw short)
__device__ __forceinline__ short bf16(float x) {
    union { float f; unsigned u; } v; v.f = x;
    unsigned u = v.u + 0x7FFFu + ((v.u >> 16) & 1u);
    return (short)(u >> 16);
}

__device__ __forceinline__ unsigned SWZ(unsigned i) {
    return i ^ ((i >> 4) & 0xFu) ^ ((i >> 8) & 0xFu);
}
__device__ __forceinline__ unsigned f1(unsigned x, unsigned m) {
    return x ^ ((x >> 1) & m);
}
__device__ __forceinline__ unsigned f2fold(unsigned x, unsigned mA, unsigned mB) {
    unsigned t = x ^ ((x >> 1) & mA);
    return t ^ ((t >> 1) & mB);
}
// inverse of gather g = f1_mB o f1_mA : apply mB first, then mA
__device__ __forceinline__ unsigned ginv(unsigned y, unsigned mB, unsigned mA) {
    unsigned t = y ^ ((y >> 1) & mB);
    return t ^ ((t >> 1) & mA);
}

__device__ __forceinline__ void crot(const f2 u00, const f2 u01,
                                     const f2 u10, const f2 u11,
                                     f2& a, f2& b) {
    const f2 sa = mkf2(-a.y, a.x);
    const f2 sb = mkf2(-b.y, b.x);
    f2 na = u00.x * a; na += u00.y * sa; na += u01.x * b; na += u01.y * sb;
    f2 nb = u10.x * a; nb += u10.y * sa; nb += u11.x * b; nb += u11.y * sb;
    a = na; b = nb;
}
__device__ __forceinline__ void apply4(f2 v[16], const f2* gU,
                                       int id0, int id1, int id2, int id3) {
    const int ids[4] = {id0, id1, id2, id3};
#pragma unroll
    for (int kk = 0; kk < 4; ++kk) {
        const int id = ids[kk];
        if (id < 0) continue;
        const f2 u00 = gU[4*id+0], u01 = gU[4*id+1];
        const f2 u10 = gU[4*id+2], u11 = gU[4*id+3];
#pragma unroll
        for (int x = 0; x < 16; ++x)
            if (!(x & (1 << kk)))
                crot(u00, u01, u10, u11, v[x], v[x | (1 << kk)]);
    }
}

__device__ __forceinline__ void prep_gates_lds(const float* __restrict__ param,
                                               f2* gU, unsigned tid) {
    if (tid < 63) {
        float phi = param[3*tid+0], th = param[3*tid+1], om = param[3*tid+2];
        float s, c;   __sincosf(0.5f*th, &s, &c);
        float sp, cp; __sincosf(-0.5f*(phi+om), &sp, &cp);
        float sm, cm; __sincosf( 0.5f*(phi-om), &sm, &cm);
        gU[4*tid+0] = mkf2( cp*c,  sp*c);
        gU[4*tid+1] = mkf2(-cm*s, -sm*s);
        gU[4*tid+2] = mkf2( cm*s, -sm*s);
        gU[4*tid+3] = mkf2( cp*c, -sp*c);
    }
}

// ---- sweep A group coordinate maps: (n 9b ctx, j 4b group) -> 13-bit e ----
__device__ __forceinline__ unsigned E1A (unsigned n, unsigned j){ return (n<<4)|j; }
__device__ __forceinline__ unsigned E2A (unsigned n, unsigned j){ return ((n>>4)<<8)|(j<<4)|(n&15u); }
__device__ __forceinline__ unsigned E3A (unsigned n, unsigned j){ return ((n>>8)<<12)|(j<<8)|(n&255u); }
__device__ __forceinline__ unsigned E4A (unsigned n, unsigned j){
    return (n&127u) | (((n>>7)&3u)<<10) | ((j&1u)<<7) | (((j>>1)&1u)<<8) | (((j>>2)&1u)<<9) | (((j>>3)&1u)<<12);
}
__device__ __forceinline__ unsigned E5A (unsigned n, unsigned j){
    return (n&31u) | (((n>>5)&7u)<<7) | (((n>>8)&1u)<<12) | ((j&1u)<<5) | (((j>>1)&1u)<<6) | (((j>>2)&1u)<<10) | (((j>>3)&1u)<<11);
}
__device__ __forceinline__ unsigned E6A (unsigned n, unsigned j){ return (n&1u) | (((n>>1)&255u)<<5) | (j<<1); }
__device__ __forceinline__ unsigned E7A (unsigned n, unsigned j){
    return ((n&63u)<<1) | (((n>>6)&7u)<<10) | (j&1u) | (((j>>1)&1u)<<7) | (((j>>2)&1u)<<8) | (((j>>3)&1u)<<9);
}
__device__ __forceinline__ unsigned E8A (unsigned n, unsigned j){ return (n&7u) | (((n>>3)&63u)<<7) | ((j&15u)<<3); }

// physical short-offset in a 32KB state buffer: [n][granule^swz][j&7]
// granule = (plane<<1 | j3) ^ ((n>>1)&3)  (bank-spread; b128-aligned granules)
__device__ __forceinline__ unsigned PHS(unsigned n, unsigned j) {
    return (n << 5) ^ ((((j >> 3) & 1u) ^ ((n >> 1) & 3u)) << 3) ^ (j & 7u);
}
// boundary write maps: e-index (prev coords) -> short-offset (plane 0)
__device__ __forceinline__ unsigned Wf2(unsigned y) {
    unsigned n = (y&15u) | (((y>>8)&31u)<<4), j = (y>>4)&15u; return PHS(n, j);
}
__device__ __forceinline__ unsigned Wf3(unsigned y) {
    unsigned n = (y&255u) | (((y>>12)&1u)<<8), j = (y>>8)&15u; return PHS(n, j);
}
__device__ __forceinline__ unsigned Wf4(unsigned y) {
    unsigned x = ginv(y, 0x2AAu, 0x155u);
    unsigned n = (x&127u) | (((x>>10)&3u)<<7);
    unsigned j = ((x>>7)&1u) | (((x>>8)&1u)<<1) | (((x>>9)&1u)<<2) | (((x>>12)&1u)<<3);
    return PHS(n, j);
}
__device__ __forceinline__ unsigned Wf5(unsigned y) {
    unsigned x = ginv(y, 0x800u, 0x400u);
    unsigned n = (x&31u) | (((x>>7)&7u)<<5) | (((x>>12)&1u)<<8);
    unsigned j = ((x>>5)&1u) | (((x>>6)&1u)<<1) | (((x>>10)&1u)<<2) | (((x>>11)&1u)<<3);
    return PHS(n, j);
}
__device__ __forceinline__ unsigned Wf6(unsigned y) {
    unsigned x = ginv(y, 0x2A0u, 0x140u);
    unsigned n = (x&1u) | (((x>>5)&255u)<<1), j = (x>>1)&15u;
    return PHS(n, j);
}
__device__ __forceinline__ unsigned Wf7(unsigned y) {
    unsigned x = ginv(y, 0x00Au, 0x014u);
    unsigned n = ((x>>1)&63u) | (((x>>10)&7u)<<6);
    unsigned j = (x&1u) | (((x>>7)&1u)<<1) | (((x>>8)&1u)<<2) | (((x>>9)&1u)<<3);
    return PHS(n, j);
}
__device__ __forceinline__ unsigned Wf8(unsigned y) {
    unsigned x = f1(y, 0x081u);
    unsigned n = (x&7u) | (((x>>7)&63u)<<3), j = (x>>3)&15u;
    return PHS(n, j);
}
__device__ __forceinline__ unsigned Wf9(unsigned y) {
    unsigned x = ginv(y, 0x028u, 0x050u);
    unsigned n = ((x>>9)&15u) | (((x>>3)&31u)<<4);
    unsigned j = (x&7u) | (((x>>8)&1u)<<3);
    return PHS(n, j);
}

__device__ __constant__ int GIDS[9][4] = {
    {20,19,18,17},{16,15,14,13},{12,11,10,9},{34,33,32,8},{36,35,31,30},
    {40,39,38,37},{41,55,54,53},{59,58,57,56},{62,61,60,-1}
};

// one MFMA group: read B (2 tiles), 2 mfma each, scatter-write via next map
#define MFMA_GRP(GIDX, CUR, EPREV, WNEXT) do { \
    const short8 A1 = *(const short8*)&Ast[((GIDX)*2+0)*512 + lan*16 + h*8]; \
    const short8 A2 = *(const short8*)&Ast[((GIDX)*2+1)*512 + lan*16 + h*8]; \
    f32x16 ac0 = {}, ac1 = {}; \
    { const short8 B1 = *(const short8*)&stb[CUR][(n0<<5) ^ ((h ^ ((n0>>1)&3u))<<3)]; \
      const short8 B2 = *(const short8*)&stb[CUR][(n0<<5) ^ (((2u|h) ^ ((n0>>1)&3u))<<3)]; \
      ac0 = __builtin_amdgcn_mfma_f32_32x32x16_bf16(A1, B1, ac0, 0, 0, 0); \
      ac0 = __builtin_amdgcn_mfma_f32_32x32x16_bf16(A2, B2, ac0, 0, 0, 0); } \
    { const short8 B1 = *(const short8*)&stb[CUR][(n1<<5) ^ ((h ^ ((n1>>1)&3u))<<3)]; \
      const short8 B2 = *(const short8*)&stb[CUR][(n1<<5) ^ (((2u|h) ^ ((n1>>1)&3u))<<3)]; \
      ac1 = __builtin_amdgcn_mfma_f32_32x32x16_bf16(A1, B1, ac1, 0, 0, 0); \
      ac1 = __builtin_amdgcn_mfma_f32_32x32x16_bf16(A2, B2, ac1, 0, 0, 0); } \
    const unsigned sb0 = WNEXT(EPREV(n0, jh)); \
    const unsigned sb1 = WNEXT(EPREV(n1, jh)); \
    _Pragma("unroll") \
    for (unsigned p = 0; p < 16; ++p) { \
        const unsigned sc = WNEXT(EPREV(0u, (p&3u) | (((p>>2)&1u)<<3))) ^ ((p>>3)<<4); \
        stb[(CUR)^1][sb0 ^ sc] = bf16(ac0[p]); \
        stb[(CUR)^1][sb1 ^ sc] = bf16(ac1[p]); \
    } \
    __syncthreads(); \
} while (0)

__global__ __launch_bounds__(512) void sweepA(const float* __restrict__ feat,
                                              const float* __restrict__ param,
                                              __half2* __restrict__ zbuf,
                                              float* __restrict__ out) {
    __shared__ short stb[2][16384];      // 2 x 32KB state (bf16)
    __shared__ short Ast[9216];          // 9 groups x {A1,A2} x 32 x 16 bf16
    __shared__ f2 gU[252];
    const unsigned tid = threadIdx.x;
    const unsigned F = blockIdx.x;                  // y bits 13..20
    const unsigned wv = tid >> 6, l = tid & 63u, lan = l & 31u, h = l >> 5;
    const unsigned n0 = wv*64u + lan, n1 = n0 + 32u;   // two 32-col tiles/wave
    const unsigned jh = h << 2;                     // j-bit2 = lane-half
    if (F == 0 && tid == 0) out[0] = 0.0f;

    // feat prefetch (issue before gate prep to hide HBM latency)
    const float4* fp0 = (const float4*)(feat + ((size_t)F << 13) + (n0 << 4) + (h << 3));
    const float4* fp1 = (const float4*)(feat + ((size_t)F << 13) + (n1 << 4) + (h << 3));
    float4 fa0 = fp0[0], fb0 = fp0[1], fa1 = fp1[0], fb1 = fp1[1];

    prep_gates_lds(param, gU, tid);
    __syncthreads();                                 // gU ready

    // build the 9 group-unitaries' A-fragments (bf16): A1=[Wr;Wi], A2=[-Wi;Wr]
    for (unsigned ent = tid; ent < 9216u; ent += 512u) {
        const unsigned g = ent >> 10, rem = ent & 1023u;
        const unsigned a12 = rem >> 9, m = (rem >> 4) & 31u, k = rem & 15u;
        const unsigned i = m & 15u, ihi = m >> 4;
        float wr = 1.f, wi = 0.f;
#pragma unroll
        for (int kk = 0; kk < 4; ++kk) {
            const int id = GIDS[g][kk];
            const unsigned ib = (i >> kk) & 1u, kb = (k >> kk) & 1u;
            if (id < 0) { if (ib != kb) { wr = 0.f; wi = 0.f; } }
            else {
                const f2 u = gU[4*id + (ib<<1) + kb];
                const float nr = wr*u.x - wi*u.y, ni = wr*u.y + wi*u.x;
                wr = nr; wi = ni;
            }
        }
        const float val = (a12 == 0) ? (ihi ? wi : wr) : (ihi ? wr : -wi);
        Ast[ent] = bf16(val);
    }
    __syncthreads();                                 // Ast ready

    // G1: B = feat (Re only, Im = 0 -> single MFMA per tile)
    {
        const short8 A1 = *(const short8*)&Ast[0*512 + lan*16 + h*8];
        f32x16 ac0 = {}, ac1 = {};
        const short8 B0 = { bf16(fa0.x), bf16(fa0.y), bf16(fa0.z), bf16(fa0.w),
                            bf16(fb0.x), bf16(fb0.y), bf16(fb0.z), bf16(fb0.w) };
        const short8 Bb = { bf16(fa1.x), bf16(fa1.y), bf16(fa1.z), bf16(fa1.w),
                            bf16(fb1.x), bf16(fb1.y), bf16(fb1.z), bf16(fb1.w) };
        ac0 = __builtin_amdgcn_mfma_f32_32x32x16_bf16(A1, B0, ac0, 0, 0, 0);
        ac1 = __builtin_amdgcn_mfma_f32_32x32x16_bf16(A1, Bb, ac1, 0, 0, 0);
        const unsigned sb0 = Wf2(E1A(n0, jh));
        const unsigned sb1 = Wf2(E1A(n1, jh));
#pragma unroll
        for (unsigned p = 0; p < 16; ++p) {
            const unsigned sc = Wf2(E1A(0u, (p&3u) | (((p>>2)&1u)<<3))) ^ ((p>>3)<<4);
            stb[0][sb0 ^ sc] = bf16(ac0[p]);
            stb[0][sb1 ^ sc] = bf16(ac1[p]);
        }
        __syncthreads();
    }
    MFMA_GRP(1, 0, E2A, Wf3);
    MFMA_GRP(2, 1, E3A, Wf4);
    MFMA_GRP(3, 0, E4A, Wf5);
    MFMA_GRP(4, 1, E5A, Wf6);
    MFMA_GRP(5, 0, E6A, Wf7);
    MFMA_GRP(6, 1, E7A, Wf8);
    MFMA_GRP(7, 0, E8A, Wf9);
    // G9: read stb[1], 2 mfma per tile, store z (fp16) directly
    {
        const short8 A1 = *(const short8*)&Ast[(8*2+0)*512 + lan*16 + h*8];
        const short8 A2 = *(const short8*)&Ast[(8*2+1)*512 + lan*16 + h*8];
        f32x16 ac0 = {}, ac1 = {};
        { const short8 B1 = *(const short8*)&stb[1][(n0<<5) ^ ((h ^ ((n0>>1)&3u))<<3)];
          const short8 B2 = *(const short8*)&stb[1][(n0<<5) ^ (((2u|h) ^ ((n0>>1)&3u))<<3)];
          ac0 = __builtin_amdgcn_mfma_f32_32x32x16_bf16(A1, B1, ac0, 0, 0, 0);
          ac0 = __builtin_amdgcn_mfma_f32_32x32x16_bf16(A2, B2, ac0, 0, 0, 0); }
        { const short8 B1 = *(const short8*)&stb[1][(n1<<5) ^ ((h ^ ((n1>>1)&3u))<<3)];
          const short8 B2 = *(const short8*)&stb[1][(n1<<5) ^ (((2u|h) ^ ((n1>>1)&3u))<<3)];
          ac1 = __builtin_amdgcn_mfma_f32_32x32x16_bf16(A1, B1, ac1, 0, 0, 0);
          ac1 = __builtin_amdgcn_mfma_f32_32x32x16_bf16(A2, B2, ac1, 0, 0, 0); }
        // store: int2 idx = n[0:3] | F<<4 | (j0:2)<<12 | n4<<15 | c<<16
        int2* zb2 = (int2*)zbuf;
        const unsigned base = (lan & 15u) | (F << 4) | (((lan >> 4) & 1u) << 15);
#pragma unroll
        for (unsigned p = 0; p < 4; ++p) {
            const unsigned jf = ((p & 3u) | (h << 2)) << 12;
            H2 y0, y1;
            y0.h[0] = __float22half2_rn(make_float2(ac0[p],      ac0[p+8]));
            y0.h[1] = __float22half2_rn(make_float2(ac0[p+4],    ac0[p+12]));
            y1.h[0] = __float22half2_rn(make_float2(ac1[p],      ac1[p+8]));
            y1.h[1] = __float22half2_rn(make_float2(ac1[p+4],    ac1[p+12]));
            zb2[base | jf | ((n0 >> 5) << 16)] = y0.i2;
            zb2[base | jf | ((n1 >> 5) << 16)] = y1.i2;
        }
    }
}

// ---- sweep B (verbatim R15, verified) ----
__device__ __forceinline__ unsigned E1Bn(unsigned t, unsigned r){ return (t&127u) | (r<<7); }
__device__ __forceinline__ unsigned E2Bn(unsigned t, unsigned r){ return (t&7u) | (r<<3) | ((t>>3)<<7); }
__device__ __forceinline__ unsigned E5Bn(unsigned t, unsigned r){
    return (t&3u) | ((r&1u)<<2) | (((t>>2)&31u)<<3) | (((r>>1)&1u)<<8) | (((r>>2)&1u)<<9) | (((r>>3)&1u)<<10);
}
__device__ __forceinline__ unsigned E6Bn(unsigned t, unsigned r){ return (t&15u) | (r<<4) | ((t>>4)<<8); }
__device__ __forceinline__ unsigned E7Bn(unsigned t, unsigned r){ return (r&15u) | (t<<4); }

template<class FW, class FR>
__device__ __forceinline__ void phase16(f2* buf, f2 v[16], unsigned tid, FW fw, FR fr) {
    const unsigned wb = fw(tid, 0u);
#pragma unroll
    for (unsigned r = 0; r < 16; ++r) buf[wb ^ fw(0u, r)] = v[r];
    __syncthreads();
    const unsigned rb = fr(tid, 0u);
#pragma unroll
    for (unsigned r = 0; r < 16; ++r) v[r] = buf[rb ^ fr(0u, r)];
}
template<class FW, class FR>
__device__ __forceinline__ void phase16_nb(f2* buf, f2 v[16], unsigned tid, FW fw, FR fr) {
    const unsigned wb = fw(tid, 0u);
#pragma unroll
    for (unsigned r = 0; r < 16; ++r) buf[wb ^ fw(0u, r)] = v[r];
    const unsigned rb = fr(tid, 0u);
#pragma unroll
    for (unsigned r = 0; r < 16; ++r) v[r] = buf[rb ^ fr(0u, r)];
}

__global__ __launch_bounds__(128, 2) void sweepB(const __half2* __restrict__ zbuf,
                                                 const float* __restrict__ param,
                                                 float* __restrict__ out) {
    __shared__ f2 sh0[2048];
    __shared__ f2 sh1[2048];
    __shared__ f2 gU[252];
    __shared__ float wsum[2];
    const unsigned tid = threadIdx.x;
    const unsigned b = ((blockIdx.x & 7u) << 6) | (blockIdx.x >> 3);  // XCD swizzle
    const unsigned B8 = (b >> 2) << 1;
    const unsigned t0 = B8 ^ ((B8 >> 1) & 5u);
    const unsigned Bp8 = t0 ^ ((t0 >> 1) & 2u);
    const unsigned zbase = (b & 1u) | (((b >> 1) & 1u) << 1) | (Bp8 << 13);

    __half2 raw[16];
    {
        const __half2* zp = zbuf + zbase + (tid << 2);
#pragma unroll
        for (int r = 0; r < 16; ++r) raw[r] = zp[(size_t)r << 9];
    }
    prep_gates_lds(param, gU, tid);

    f2 v[16];
#pragma unroll
    for (int r = 0; r < 16; ++r) {
        float2 t2 = __half22float2(raw[r]);
        v[r] = mkf2(t2.x, t2.y);
    }
    __syncthreads();
    apply4(v, gU, 3, 2, 1, 0);
    phase16(sh1, v, tid,
        [](unsigned t, unsigned r){ return SWZ(E1Bn(t,r)); },
        [](unsigned t, unsigned r){ return SWZ(f1(E2Bn(t,r), 0x280u)); });
    apply4(v, gU, 7, 6, 5, 4);
    phase16(sh0, v, tid,
        [](unsigned t, unsigned r){ return SWZ(E2Bn(t,r)); },
        [](unsigned t, unsigned r){ return SWZ(f2fold(E1Bn(t,r), 0x154u, 0x028u)); });
    apply4(v, gU, 24, 23, 22, 21);
    phase16(sh1, v, tid,
        [](unsigned t, unsigned r){ return SWZ(E1Bn(t,r)); },
        [](unsigned t, unsigned r){ return SWZ(f1(E2Bn(t,r), 0x280u)); });
    apply4(v, gU, 28, 27, 26, 25);
    phase16(sh0, v, tid,
        [](unsigned t, unsigned r){ return SWZ(E2Bn(t,r)); },
        [](unsigned t, unsigned r){ return SWZ(f2fold(E5Bn(t,r), 0x150u, 0x028u)); });
    apply4(v, gU, 29, 44, 43, 42);
    phase16(sh1, v, tid,
        [](unsigned t, unsigned r){ return SWZ(E5Bn(t,r)); },
        [](unsigned t, unsigned r){ return SWZ(f2fold(E6Bn(t,r), 0x005u, 0x002u)); });
    apply4(v, gU, 48, 47, 46, 45);
    phase16_nb(sh0, v, tid,
        [](unsigned t, unsigned r){ return SWZ(E6Bn(t,r)); },
        [](unsigned t, unsigned r){ return SWZ(E7Bn(t,r)); });
    apply4(v, gU, 52, 51, 50, 49);
    float acc = 0.f;
#pragma unroll
    for (int r = 0; r < 16; ++r) acc += v[r].x*v[r].x + v[r].y*v[r].y;
    for (int off = 32; off; off >>= 1) acc += __shfl_down(acc, off);
    if ((tid & 63u) == 0) wsum[tid >> 6] = acc;
    __syncthreads();
    if (tid == 0) atomicAdd(out, wsum[0] + wsum[1]);
}

extern "C" void kernel_launch(void* const* d_in, const int* in_sizes, int n_in,
                              void* d_out, int out_size, void* d_ws, size_t ws_size,
                              hipStream_t stream) {
    const float* feat  = (const float*)d_in[0];
    const float* param = (const float*)d_in[1];
    float* out = (float*)d_out;
    __half2* zbuf = (__half2*)d_ws;                // 2^21 * 4B = 8 MB

    sweepA<<<256, 512, 0, stream>>>(feat, param, zbuf, out);
    sweepB<<<512, 128, 0, stream>>>(zbuf, param, out);
}